// Round 16
// baseline (4727.693 us; speedup 1.0000x reference)
//
#include <hip/hip_runtime.h>

// ---------------------------------------------------------------------------
// Persistent weight-stationary LSTM, bf16 MFMA, per-layer decoupled sync.
// T=1024 B=64 C=256 H=512, 2 layers, fp32 in/out.
//  - 256 blocks x 256 threads, 1 block/CU; blocks 0..127 = layer0 (step t),
//    128..255 = layer1 (step t-1). Block=(layer,bg,cg): 16 batches x 16 cols.
//  - SYNC: per (bg) group, per LAYER counters (2 lines x 16 blocks each).
//    h0 is a 4-deep ring (ws permitting; else 2-deep lockstep fallback):
//    L0 tail(i) waits L0cnt>=16(i+1) && L1cnt>=16(i+1-slack) (slack=2);
//    L1 tail(i) waits L0cnt>=16(i+1) && L1cnt>=16(i+1).
//    Steady state: L0 runs up to 2 ahead; each layer paced by its OWN
//    32-block join (L1 no longer absorbs L0 jitter and vice versa).
//    Hazard audit: slot (j+1)&3 written by L0@j; stale readers L0@j-3
//    (gated by L0cnt>=16j) and L1@j-3 (gated by L1cnt>=16(j-2)). h1 depth-2
//    anti-dep gated by L1cnt>=16i. All covered.
//  - h layout [cg][w][b][4c] u64: producer wave's 16 jj==0 stores are
//    CONTIGUOUS 128B -> full-line direct stores; hstage LDS merge + one
//    __syncthreads deleted. Consumer staging: 128B chunks per (cg,w).
//  - L1 split staging: h1 loads -> h0 loads -> vmcnt(4) -> stage h1 -> sync
//    -> h1 MFMAs (h0 still in flight) -> vmcnt(0) -> stage h0 -> sync -> h0.
//  - Rest as R15: XOR-swizzled LDS A-frags, W pinned in VGPRs, counter-join
//    arithmetic, float4 out, x reg-prefetch.
//  - mfma_f32_16x16x32_bf16: A[m=lane&15][k=quad*8+j], B(N,K)[n=lane&15][k=quad*8+j],
//    D[m=quad*4+reg][n=lane&15]  (guide-verified mapping, m90/m97 convention)
// ---------------------------------------------------------------------------

#define TT 1024
#define BB 64
#define CC 256
#define HH 512
#define Y_ELEMS (TT * BB * HH)
#define S_ELEMS (BB * HH)
#define H_SLOT 65536

typedef __attribute__((ext_vector_type(8))) short bf16x8;
typedef __attribute__((ext_vector_type(4))) float f32x4;
typedef unsigned int u32;
typedef unsigned short u16;
typedef unsigned long long u64;

// ---- ws layout (byte offsets; h/wpk offsets runtime-computed) ----
// [0,2048)        16 counter lines * 128B
// [4096,12288)    bsum0 (2048 f32)
// [12288,20480)   bsum1 (2048 f32)
// [20480,...)     h0 ring: (m0+1) slots * 65536
// h1off           h1: 2 slots * 65536
// wpk0off         layer0 packed W (3,145,728)
// wpk1off         layer1 packed W (4,194,304)
// 4-deep total 7,753,728 ; 2-deep fallback 7,622,656

__device__ __forceinline__ u16 f2b_rne(float f) {
    u32 u = __float_as_uint(f);
    return (u16)((u + 0x7FFFu + ((u >> 16) & 1u)) >> 16);
}
__device__ __forceinline__ u16 f2b_fast(float f) {
    return (u16)((__float_as_uint(f) + 0x8000u) >> 16);
}
__device__ __forceinline__ float sigf(float z) { return 1.0f / (1.0f + __expf(-z)); }
__device__ __forceinline__ float tanh_f(float z) { return 2.0f / (1.0f + __expf(-2.0f * z)) - 1.0f; }

__device__ __forceinline__ bf16x8 pack8(float4 a, float4 b) {
    union { u16 u[8]; bf16x8 v; } r;
    r.u[0] = f2b_fast(a.x); r.u[1] = f2b_fast(a.y); r.u[2] = f2b_fast(a.z); r.u[3] = f2b_fast(a.w);
    r.u[4] = f2b_fast(b.x); r.u[5] = f2b_fast(b.y); r.u[6] = f2b_fast(b.z); r.u[7] = f2b_fast(b.w);
    return r.v;
}

__device__ __forceinline__ u32 ld_u32_sc(const u32* p) {
    return __hip_atomic_load(p, __ATOMIC_RELAXED, __HIP_MEMORY_SCOPE_AGENT);
}
__device__ __forceinline__ void add_u32_sc(u32* p, u32 v) {
    (void)__hip_atomic_fetch_add(p, v, __ATOMIC_RELAXED, __HIP_MEMORY_SCOPE_AGENT);
}

// ---- init ---- h element (b,col) -> u16 idx cg*1024 + w*256 + b*4 + j
__global__ void k_init(const float* __restrict__ bih0, const float* __restrict__ bhh0,
                       const float* __restrict__ bih1, const float* __restrict__ bhh1,
                       const float* __restrict__ h00, const float* __restrict__ h01,
                       unsigned char* __restrict__ ws, u64 h1off) {
    float* bs0 = (float*)(ws + 4096);
    float* bs1 = (float*)(ws + 12288);
    u16* h0 = (u16*)(ws + 20480);
    u16* h1 = (u16*)(ws + h1off);
    int t = blockIdx.x * 256 + threadIdx.x;  // 32768 threads
    if (t < 1024) ((u32*)ws)[t] = 0u;        // counter region
    if (t < 2048) { bs0[t] = bih0[t] + bhh0[t]; bs1[t] = bih1[t] + bhh1[t]; }
    if (t < S_ELEMS) {
        int b = t >> 9, col = t & 511;
        int no = ((col >> 4) << 10) + (((col >> 2) & 3) << 8) + (b << 2) + (col & 3);
        h0[no] = f2b_rne(h00[t]);
        h1[no] = f2b_rne(h01[t]);
    }
}

// ---- weight pack (math unchanged; dst offsets runtime) ----
__global__ void k_wprep(const float* __restrict__ Wih0, const float* __restrict__ Whh0,
                        const float* __restrict__ Wih1, const float* __restrict__ Whh1,
                        unsigned char* __restrict__ ws, u64 wpk0off, u64 wpk1off) {
    u16* wpk0 = (u16*)(ws + wpk0off);
    u16* wpk1 = (u16*)(ws + wpk1off);
    int u = blockIdx.x * 256 + threadIdx.x;  // 458752 threads
    const float* s;
    u16* d;
    if (u < 128 * 24 * 64) {
        int bidL = u / (24 * 64);
        int kt = (u >> 6) % 24;
        int lane = u & 63;
        int n = lane & 15, quad = lane >> 4;
        int row = (n >> 2) * 512 + bidL * 4 + (n & 3);
        int k = kt * 32 + quad * 8;
        s = (k < 256) ? (Wih0 + (size_t)row * 256 + k) : (Whh0 + (size_t)row * 512 + (k - 256));
        d = wpk0 + (size_t)((bidL * 24 + kt) * 64 + lane) * 8;
    } else {
        int v = u - 128 * 24 * 64;
        int bidL = v / (32 * 64);
        int kt = (v >> 6) % 32;
        int lane = v & 63;
        int n = lane & 15, quad = lane >> 4;
        int row = (n >> 2) * 512 + bidL * 4 + (n & 3);
        int k = kt * 32 + quad * 8;
        s = (k < 512) ? (Wih1 + (size_t)row * 512 + k) : (Whh1 + (size_t)row * 512 + (k - 512));
        d = wpk1 + (size_t)((bidL * 32 + kt) * 64 + lane) * 8;
    }
    #pragma unroll
    for (int i = 0; i < 8; ++i) d[i] = f2b_rne(s[i]);
}

// ---- persistent tick loop ----
template <int LAYER>
__device__ void run_ticks(const float* __restrict__ x, const float* __restrict__ c0,
                          float* __restrict__ out, unsigned char* __restrict__ ws,
                          int bidL, unsigned char* lds,
                          u32 m0, u32 slack, u64 h1off, u64 wpkoff) {
    constexpr int NKT = (LAYER == 0) ? 24 : 32;
    u32* cnt = (u32*)ws;
    const float* bs = (const float*)(ws + (LAYER == 0 ? 4096 : 12288));
    unsigned char* h0base = ws + 20480;
    unsigned char* h1base = ws + h1off;
    const u16* wpk = (const u16*)(ws + wpkoff);

    const int bg = bidL >> 5, cg = bidL & 31;
    const int tid = threadIdx.x, lane = tid & 63, wave = tid >> 6;
    const int r16 = lane & 15, quad = lane >> 4, q8 = quad * 8;
    const int gg = r16 >> 2, jj = r16 & 3;
    const int col = cg * 16 + wave * 4 + jj;
    const int mb = quad * 4 + gg;
    const int myb = bg * 16 + mb;
    const int sl0 = (quad << 4) | (0 << 2) | jj;
    const int sl1 = (quad << 4) | (1 << 2) | jj;
    const int sl2 = (quad << 4) | (2 << 2) | jj;
    const int sl3 = (quad << 4) | (3 << 2) | jj;
    const int baseln = (quad << 4) | (gg << 2);
    const int sw = (r16 & 7) << 4;

    u32* gl = cnt + (u32)bg * 4 * 32;                       // group's 4 lines
    u32* mycnt = gl + (u32)(LAYER * 2 + (cg & 1)) * 32;

    const float bi = bs[0 * HH + col], bf_ = bs[1 * HH + col];
    const float bg_ = bs[2 * HH + col], bo = bs[3 * HH + col];
    float c = c0[myb * HH + col];

    // weight fragments: tile v = cg*4 + wave
    f32x4 wf[NKT];
    {
        const u16* wp = wpk + (size_t)((cg * 4 + wave) * NKT * 64 + lane) * 8;
        #pragma unroll
        for (int kt = 0; kt < NKT; ++kt) wf[kt] = *(const f32x4*)(wp + (size_t)kt * 64 * 8);
        #pragma unroll
        for (int kt = 0; kt < NKT; ++kt) asm volatile("" : "+v"(wf[kt]));
    }

    // LDS write of one 16B staged chunk (two swizzled b64 writes)
    auto wr2 = [&](f32x4 v, int g, int base) {
        union { f32x4 v4; u64 q[2]; } uu; uu.v4 = v;
        int cgi = g >> 9, w = (g >> 7) & 3, rem = g & 127;
        int a = rem >> 4;
        #pragma unroll
        for (int e = 0; e < 2; ++e) {
            int m = a * 2 + e;
            int lo = (cgi * 32 + w * 8) ^ ((m & 7) << 4);
            *(u64*)(lds + base + m * 1024 + lo) = uu.q[e];
        }
    };

    // layer0: x prefetch registers
    float4 xf0[8], xf1[8];
    if (LAYER == 0) {
        const float* xp = x + (size_t)(bg * 16 + r16) * CC + q8;
        #pragma unroll
        for (int kt = 0; kt < 8; ++kt) {
            xf0[kt] = *(const float4*)(xp + kt * 32);
            xf1[kt] = *(const float4*)(xp + kt * 32 + 4);
        }
    }

    for (int i = 0; i <= TT; ++i) {
        const bool active = (LAYER == 0) ? (i < TT) : (i >= 1);
        const int t = (LAYER == 0) ? i : i - 1;
        float h = 0.f;
        if (active) {
            f32x4 a0 = {0.f,0.f,0.f,0.f}, a1 = {0.f,0.f,0.f,0.f};
            f32x4 a2 = {0.f,0.f,0.f,0.f}, a3 = {0.f,0.f,0.f,0.f};
            if (LAYER == 0) {
                f32x4 stg[4];
                const char* srcA = (const char*)h0base + (size_t)((u32)t & m0) * H_SLOT;
                #pragma unroll
                for (int k = 0; k < 4; ++k) {
                    int g = k * 4096 + tid * 16;
                    const char* sp = srcA + (g >> 9) * 2048 + ((g >> 7) & 3) * 512
                                   + bg * 128 + (g & 127);
                    asm volatile("global_load_dwordx4 %0, %1, off sc0 sc1"
                                 : "=&v"(stg[k]) : "v"(sp) : "memory");
                }
                // x projection overlaps staging flight
                #pragma unroll
                for (int kt = 0; kt < 8; ++kt) {
                    bf16x8 a = pack8(xf0[kt], xf1[kt]);
                    bf16x8 wv = __builtin_bit_cast(bf16x8, wf[kt]);
                    f32x4& dst = (kt & 2) ? ((kt & 1) ? a3 : a2) : ((kt & 1) ? a1 : a0);
                    dst = __builtin_amdgcn_mfma_f32_16x16x32_bf16(a, wv, dst, 0, 0, 0);
                }
                asm volatile("s_waitcnt vmcnt(0)" ::: "memory");
                __builtin_amdgcn_sched_barrier(0);
                #pragma unroll
                for (int k = 0; k < 4; ++k) wr2(stg[k], k * 4096 + tid * 16, 0);
                __syncthreads();
                #pragma unroll
                for (int kt = 0; kt < 16; ++kt) {
                    bf16x8 av = *(const bf16x8*)(lds + r16 * 1024 + ((kt * 64 + quad * 16) ^ sw));
                    bf16x8 wv = __builtin_bit_cast(bf16x8, wf[8 + kt]);
                    f32x4& dst = (kt & 2) ? ((kt & 1) ? a3 : a2) : ((kt & 1) ? a1 : a0);
                    dst = __builtin_amdgcn_mfma_f32_16x16x32_bf16(av, wv, dst, 0, 0, 0);
                }
            } else {
                f32x4 stgB[4], stgA[4];
                const char* srcB = (const char*)h1base + (size_t)((u32)t & 1) * H_SLOT;
                const char* srcA = (const char*)h0base + (size_t)((u32)(t + 1) & m0) * H_SLOT;
                #pragma unroll
                for (int k = 0; k < 4; ++k) {       // h1 first
                    int g = k * 4096 + tid * 16;
                    const char* sp = srcB + (g >> 9) * 2048 + ((g >> 7) & 3) * 512
                                   + bg * 128 + (g & 127);
                    asm volatile("global_load_dwordx4 %0, %1, off sc0 sc1"
                                 : "=&v"(stgB[k]) : "v"(sp) : "memory");
                }
                #pragma unroll
                for (int k = 0; k < 4; ++k) {       // h0 (y0) second
                    int g = k * 4096 + tid * 16;
                    const char* sp = srcA + (g >> 9) * 2048 + ((g >> 7) & 3) * 512
                                   + bg * 128 + (g & 127);
                    asm volatile("global_load_dwordx4 %0, %1, off sc0 sc1"
                                 : "=&v"(stgA[k]) : "v"(sp) : "memory");
                }
                asm volatile("s_waitcnt vmcnt(4)" ::: "memory");   // h1 done
                __builtin_amdgcn_sched_barrier(0);
                #pragma unroll
                for (int k = 0; k < 4; ++k) wr2(stgB[k], k * 4096 + tid * 16, 16384);
                __syncthreads();
                #pragma unroll
                for (int kt = 16; kt < 32; ++kt) {  // h1 MFMAs overlap h0 flight
                    bf16x8 av = *(const bf16x8*)(lds + 16384 + r16 * 1024
                                                 + (((kt & 15) * 64 + quad * 16) ^ sw));
                    bf16x8 wv = __builtin_bit_cast(bf16x8, wf[kt]);
                    f32x4& dst = (kt & 2) ? ((kt & 1) ? a3 : a2) : ((kt & 1) ? a1 : a0);
                    dst = __builtin_amdgcn_mfma_f32_16x16x32_bf16(av, wv, dst, 0, 0, 0);
                }
                asm volatile("s_waitcnt vmcnt(0)" ::: "memory");
                __builtin_amdgcn_sched_barrier(0);
                #pragma unroll
                for (int k = 0; k < 4; ++k) wr2(stgA[k], k * 4096 + tid * 16, 0);
                __syncthreads();
                #pragma unroll
                for (int kt = 0; kt < 16; ++kt) {
                    bf16x8 av = *(const bf16x8*)(lds + r16 * 1024 + ((kt * 64 + quad * 16) ^ sw));
                    bf16x8 wv = __builtin_bit_cast(bf16x8, wf[kt]);
                    f32x4& dst = (kt & 2) ? ((kt & 1) ? a3 : a2) : ((kt & 1) ? a1 : a0);
                    dst = __builtin_amdgcn_mfma_f32_16x16x32_bf16(av, wv, dst, 0, 0, 0);
                }
            }
            f32x4 acc = (a0 + a1) + (a2 + a3);

            float gi = 0.f, gf = 0.f, gc = 0.f, go = 0.f;
            #pragma unroll
            for (int r = 0; r < 4; ++r) {
                float v0 = __shfl(acc[r], sl0, 64);
                float v1 = __shfl(acc[r], sl1, 64);
                float v2 = __shfl(acc[r], sl2, 64);
                float v3 = __shfl(acc[r], sl3, 64);
                if (r == gg) { gi = v0; gf = v1; gc = v2; go = v3; }
            }
            gi = sigf(gi + bi);
            gf = sigf(gf + bf_);
            gc = tanh_f(gc + bg_);
            go = sigf(go + bo);
            c = gf * c + gi * gc;
            h = go * tanh_f(c);

            // direct full-line h store: wave's 16 jj==0 u64s are 128B contiguous
            u32 w0 = f2b_rne(h);
            u32 w1 = (u32)__shfl((int)w0, baseln + 1, 64);
            u32 w2 = (u32)__shfl((int)w0, baseln + 2, 64);
            u32 w3 = (u32)__shfl((int)w0, baseln + 3, 64);
            if (jj == 0) {
                u64 pkd = (u64)(w0 | (w1 << 16)) | ((u64)(w2 | (w3 << 16)) << 32);
                unsigned char* hb = (LAYER == 0)
                    ? h0base + (size_t)((u32)(t + 1) & m0) * H_SLOT
                    : h1base + (size_t)((u32)(t + 1) & 1) * H_SLOT;
                u64* dp = (u64*)(hb + cg * 2048 + wave * 512 + bg * 128 + mb * 8);
                __hip_atomic_store(dp, pkd, __ATOMIC_RELAXED, __HIP_MEMORY_SCOPE_AGENT);
            }
        }
        // ---- arrival: drain, then one relaxed fetch-add ----
        if (i < TT) {
            asm volatile("s_waitcnt vmcnt(0)" ::: "memory");
            __syncthreads();
            if (tid == 0) add_u32_sc(mycnt, 1u);
        }
        // ---- shadow work ----
        if (active) {
            if (LAYER == 1) {
                float o1 = __shfl(h, baseln + 1, 64);
                float o2 = __shfl(h, baseln + 2, 64);
                float o3 = __shfl(h, baseln + 3, 64);
                if (jj == 0) {
                    float4 ov = { h, o1, o2, o3 };
                    *(float4*)(out + (size_t)t * S_ELEMS + (size_t)myb * HH
                               + cg * 16 + wave * 4) = ov;
                }
            }
            if (t == TT - 1) {
                float* fin = out + Y_ELEMS + (LAYER == 0 ? 0 : 2) * S_ELEMS;
                fin[myb * HH + col] = h;
                fin[S_ELEMS + myb * HH + col] = c;
            }
        }
        if (LAYER == 0 && i + 1 < TT) {
            const float* xp = x + ((size_t)(i + 1) * BB + bg * 16 + r16) * CC + q8;
            #pragma unroll
            for (int kt = 0; kt < 8; ++kt) {
                xf0[kt] = *(const float4*)(xp + kt * 32);
                xf1[kt] = *(const float4*)(xp + kt * 32 + 4);
            }
        }
        // ---- completion: per-layer thresholds ----
        if (i < TT) {
            if (tid == 0) {
                const u32 tO = 16u * (u32)(i + 1);
                u32 tC;
                if (LAYER == 0) {
                    u32 j = (u32)(i + 1);
                    tC = (j > slack) ? 16u * (j - slack) : 0u;
                } else {
                    tC = tO;    // L1 needs own siblings at full step
                }
                while (true) {
                    u32 a = ld_u32_sc(gl + 0);       // L0 line a
                    u32 b = ld_u32_sc(gl + 32);      // L0 line b
                    u32 e = ld_u32_sc(gl + 64);      // L1 line a
                    u32 d = ld_u32_sc(gl + 96);      // L1 line b
                    u32 mA = min(a, b), mB = min(e, d);
                    bool ok = (LAYER == 0) ? (mA >= tO && mB >= tC)
                                           : (mA >= tO && mB >= tC);
                    if (ok) break;
                }
            }
            __syncthreads();
        }
    }
}

__global__ __launch_bounds__(256) __attribute__((amdgpu_waves_per_eu(1, 1)))
void k_lstm(const float* __restrict__ x,
            const float* __restrict__ c00,
            const float* __restrict__ c01,
            float* __restrict__ out,
            unsigned char* __restrict__ ws,
            u32 m0, u32 slack, u64 h1off, u64 wpk0off, u64 wpk1off) {
    __shared__ __align__(16) unsigned char lds[32768];
    const int bid = blockIdx.x;
    if (bid < 128) run_ticks<0>(x, c00, out, ws, bid, lds, m0, slack, h1off, wpk0off);
    else           run_ticks<1>(x, c01, out, ws, bid - 128, lds, m0, slack, h1off, wpk1off);
}

extern "C" void kernel_launch(void* const* d_in, const int* in_sizes, int n_in,
                              void* d_out, int out_size, void* d_ws, size_t ws_size,
                              hipStream_t stream) {
    const float* x    = (const float*)d_in[0];
    const float* h0_0 = (const float*)d_in[1];
    const float* c0_0 = (const float*)d_in[2];
    const float* h0_1 = (const float*)d_in[3];
    const float* c0_1 = (const float*)d_in[4];
    const float* Wih0 = (const float*)d_in[5];
    const float* Whh0 = (const float*)d_in[6];
    const float* bih0 = (const float*)d_in[7];
    const float* bhh0 = (const float*)d_in[8];
    const float* Wih1 = (const float*)d_in[9];
    const float* Whh1 = (const float*)d_in[10];
    const float* bih1 = (const float*)d_in[11];
    const float* bhh1 = (const float*)d_in[12];
    float* out = (float*)d_out;
    unsigned char* ws = (unsigned char*)d_ws;

    // 4-deep h0 ring needs 7,753,728 B; else 2-deep lockstep fallback.
    const u64 NEED4 = 20480ull + 6ull * H_SLOT + 3145728ull + 4194304ull + 131072ull; // 7,753,728
    const bool big = (u64)ws_size >= NEED4;
    const u32 m0 = big ? 3u : 1u;
    const u32 slack = big ? 2u : 0u;
    const u64 h0off = 20480ull;
    const u64 h1off = h0off + (u64)(m0 + 1u) * H_SLOT;
    const u64 wpk0off = h1off + 2ull * H_SLOT;
    const u64 wpk1off = wpk0off + 3145728ull;

    k_init<<<128, 256, 0, stream>>>(bih0, bhh0, bih1, bhh1, h0_0, h0_1, ws, h1off);
    k_wprep<<<1792, 256, 0, stream>>>(Wih0, Whh0, Wih1, Whh1, ws, wpk0off, wpk1off);
    k_lstm<<<256, 256, 0, stream>>>(x, c0_0, c0_1, out, ws, m0, slack, h1off, wpk0off, wpk1off);
}

// Round 17
// 4573.308 us; speedup vs baseline: 1.0338x; 1.0338x over previous
//
#include <hip/hip_runtime.h>

// ---------------------------------------------------------------------------
// Persistent weight-stationary LSTM, bf16 MFMA, shared-A blocks, PER-GROUP sync.
// T=1024 B=64 C=256 H=512, 2 layers, fp32 in/out.  (R15 base + 2 overlaps)
//  - 256 blocks x 256 threads, 1 block/CU; blocks 0..127 = layer0 (step t),
//    128..255 = layer1 (step t-1). Block = (layer, bg, cg): 16 batches
//    (bg of 4) x 16 cols (cg of 32); 4 waves share staged A rows.
//  - Per-batch-group barrier (R15): group bg = 64 blocks with 4 counter
//    lines (16 blocks each); relaxed fetch-add arrival, poll for 16*(i+1).
//  - NEW 1 (vs R15): L1 split staging -- h1 loads issued first, vmcnt(4),
//    stage h1, run the 16 h1-MFMAs while h0 loads still in flight, then
//    vmcnt(0), stage h0, h0-MFMAs. Hides part of the staging round on the
//    slower layer. fp32 accumulation reorder only (tolerance-proven).
//  - NEW 2: completion poll on tid 67 (jj=3: no out/hstage shadow stores)
//    so polling starts immediately after the arrival add.
//  - Everything else byte-identical to R15: LDS A-staging (XOR-swizzled),
//    [cg][b][16c] u64 h layout w/ LDS-merged full-line stores, W in VGPRs,
//    float4 out, x reg-prefetch.
//  - mfma_f32_16x16x32_bf16: A[m=lane&15][k=quad*8+j], B(N,K)[n=lane&15][k=quad*8+j],
//    D[m=quad*4+reg][n=lane&15]  (guide-verified mapping, m90/m97 convention)
// ---------------------------------------------------------------------------

#define TT 1024
#define BB 64
#define CC 256
#define HH 512
#define Y_ELEMS (TT * BB * HH)
#define S_ELEMS (BB * HH)

typedef __attribute__((ext_vector_type(8))) short bf16x8;
typedef __attribute__((ext_vector_type(4))) float f32x4;
typedef unsigned int u32;
typedef unsigned short u16;
typedef unsigned long long u64;

// ---- ws layout (bytes) ----
#define WS_BAR 0           // (legacy, unused)
#define WS_CNT 32768       // 16 counter lines * 128B (4 per batch-group)
#define WS_BSUM0 36864     // 2048 f32
#define WS_BSUM1 45056     // 2048 f32
#define WS_H0 53248        // 2 * 65536 B  (h0 ping-pong, [32cg][64b][16c] u16)
#define WS_H1 184320       // 2 * 65536 B  (h1 ping-pong, same layout)
#define WS_WPK0 315392     // 128*24*64*8 bf16  (layer0 packed W)
#define WS_WPK1 3461120    // 128*32*64*8 bf16  (layer1 packed W)
// end 7655424 (~7.66 MB)

__device__ __forceinline__ u16 f2b_rne(float f) {
    u32 u = __float_as_uint(f);
    return (u16)((u + 0x7FFFu + ((u >> 16) & 1u)) >> 16);
}
__device__ __forceinline__ u16 f2b_fast(float f) {  // round-half-up, 2 ops
    return (u16)((__float_as_uint(f) + 0x8000u) >> 16);
}
__device__ __forceinline__ float sigf(float z) { return 1.0f / (1.0f + __expf(-z)); }
__device__ __forceinline__ float tanh_f(float z) { return 2.0f / (1.0f + __expf(-2.0f * z)) - 1.0f; }

__device__ __forceinline__ bf16x8 pack8(float4 a, float4 b) {
    union { u16 u[8]; bf16x8 v; } r;
    r.u[0] = f2b_fast(a.x); r.u[1] = f2b_fast(a.y); r.u[2] = f2b_fast(a.z); r.u[3] = f2b_fast(a.w);
    r.u[4] = f2b_fast(b.x); r.u[5] = f2b_fast(b.y); r.u[6] = f2b_fast(b.z); r.u[7] = f2b_fast(b.w);
    return r.v;
}

__device__ __forceinline__ u32 ld_u32_sc(const u32* p) {
    return __hip_atomic_load(p, __ATOMIC_RELAXED, __HIP_MEMORY_SCOPE_AGENT);
}
__device__ __forceinline__ void add_u32_sc(u32* p, u32 v) {
    (void)__hip_atomic_fetch_add(p, v, __ATOMIC_RELAXED, __HIP_MEMORY_SCOPE_AGENT);
}

// ---- init: zero counters, bsum = bih+bhh, h slot0 <- bf16(h_init) ----
// layout: (b,col) -> u16 index (col>>4)*1024 + b*16 + (col&15)
__global__ void k_init(const float* __restrict__ bih0, const float* __restrict__ bhh0,
                       const float* __restrict__ bih1, const float* __restrict__ bhh1,
                       const float* __restrict__ h00, const float* __restrict__ h01,
                       unsigned char* __restrict__ ws) {
    u32* bar = (u32*)(ws + WS_BAR);
    float* bs0 = (float*)(ws + WS_BSUM0);
    float* bs1 = (float*)(ws + WS_BSUM1);
    u16* h0 = (u16*)(ws + WS_H0);
    u16* h1 = (u16*)(ws + WS_H1);
    int t = blockIdx.x * 256 + threadIdx.x;  // 32768 threads
    if (t < 8704) bar[t] = 0u;               // legacy flags + 16 counter lines
    if (t < 2048) { bs0[t] = bih0[t] + bhh0[t]; bs1[t] = bih1[t] + bhh1[t]; }
    if (t < S_ELEMS) {
        int b = t >> 9, col = t & 511;
        int no = ((col >> 4) << 10) + (b << 4) + (col & 15);
        h0[no] = f2b_rne(h00[t]);
        h1[no] = f2b_rne(h01[t]);
    }
}

// ---- weight pack (UNCHANGED): tile v in [0,128) owns cols v*4..v*4+3 ----
__global__ void k_wprep(const float* __restrict__ Wih0, const float* __restrict__ Whh0,
                        const float* __restrict__ Wih1, const float* __restrict__ Whh1,
                        unsigned char* __restrict__ ws) {
    u16* wpk0 = (u16*)(ws + WS_WPK0);
    u16* wpk1 = (u16*)(ws + WS_WPK1);
    int u = blockIdx.x * 256 + threadIdx.x;  // 458752 threads
    const float* s;
    u16* d;
    if (u < 128 * 24 * 64) {  // layer0: 8 x-tiles (K=256) + 16 h-tiles (K=512)
        int bidL = u / (24 * 64);
        int kt = (u >> 6) % 24;
        int lane = u & 63;
        int n = lane & 15, quad = lane >> 4;
        int row = (n >> 2) * 512 + bidL * 4 + (n & 3);
        int k = kt * 32 + quad * 8;
        s = (k < 256) ? (Wih0 + (size_t)row * 256 + k) : (Whh0 + (size_t)row * 512 + (k - 256));
        d = wpk0 + (size_t)((bidL * 24 + kt) * 64 + lane) * 8;
    } else {  // layer1: 16 y0-tiles + 16 h1-tiles (K=1024)
        int v = u - 128 * 24 * 64;
        int bidL = v / (32 * 64);
        int kt = (v >> 6) % 32;
        int lane = v & 63;
        int n = lane & 15, quad = lane >> 4;
        int row = (n >> 2) * 512 + bidL * 4 + (n & 3);
        int k = kt * 32 + quad * 8;
        s = (k < 512) ? (Wih1 + (size_t)row * 512 + k) : (Whh1 + (size_t)row * 512 + (k - 512));
        d = wpk1 + (size_t)((bidL * 32 + kt) * 64 + lane) * 8;
    }
    #pragma unroll
    for (int i = 0; i < 8; ++i) d[i] = f2b_rne(s[i]);
}

// ---- the persistent tick loop, templated on layer ----
// lds: [0,32768) staged A rows (swizzled); [32768,33280) hstage (512 B)
template <int LAYER>
__device__ void run_ticks(const float* __restrict__ x, const float* __restrict__ c0,
                          float* __restrict__ out, unsigned char* __restrict__ ws,
                          int bidL, unsigned char* lds) {
    constexpr int NKT = (LAYER == 0) ? 24 : 32;
    constexpr int NL = (LAYER == 0) ? 4 : 8;      // staging 16B-loads per thread
    u32* cnt = (u32*)(ws + WS_CNT);               // 16 lines, stride 32 u32
    const float* bs = (const float*)(ws + (LAYER == 0 ? WS_BSUM0 : WS_BSUM1));
    u16* h0base = (u16*)(ws + WS_H0);
    u16* h1base = (u16*)(ws + WS_H1);
    const u16* wpk = (const u16*)(ws + (LAYER == 0 ? WS_WPK0 : WS_WPK1));

    const int bg = bidL >> 5;                 // batch group [0,4) -- sync group
    const int cg = bidL & 31;                 // col group  [0,32)
    const int tid = threadIdx.x, lane = tid & 63, wave = tid >> 6;
    const int r16 = lane & 15, quad = lane >> 4, q8 = quad * 8;
    const int gg = r16 >> 2, jj = r16 & 3;
    const int col = cg * 16 + wave * 4 + jj;  // h column this lane finalizes
    const int mb = quad * 4 + gg;             // local batch this lane finalizes
    const int myb = bg * 16 + mb;             // global batch
    const int sl0 = (quad << 4) | (0 << 2) | jj;
    const int sl1 = (quad << 4) | (1 << 2) | jj;
    const int sl2 = (quad << 4) | (2 << 2) | jj;
    const int sl3 = (quad << 4) | (3 << 2) | jj;
    const int baseln = (quad << 4) | (gg << 2);   // lane jj=0 of my (quad,gg) group

    u16* hstage = (u16*)(lds + 32768);
    const int sw = (r16 & 7) << 4;            // frag-read XOR swizzle

    // per-group barrier: group bg's 4 lines; 16 blocks arrive per line
    u32* gcnt = cnt + (u32)bg * 4 * 32;
    u32* mycnt = gcnt + (u32)((LAYER * 32 + cg) & 3) * 32;

    // biases (hoisted), c state in register for the whole run
    const float bi = bs[0 * HH + col], bf_ = bs[1 * HH + col];
    const float bg_ = bs[2 * HH + col], bo = bs[3 * HH + col];
    float c = c0[myb * HH + col];

    // weight fragments: tile v = cg*4 + wave (wpk layout unchanged)
    f32x4 wf[NKT];
    {
        const u16* wp = wpk + (size_t)((cg * 4 + wave) * NKT * 64 + lane) * 8;
        #pragma unroll
        for (int kt = 0; kt < NKT; ++kt) wf[kt] = *(const f32x4*)(wp + (size_t)kt * 64 * 8);
        #pragma unroll
        for (int kt = 0; kt < NKT; ++kt) asm volatile("" : "+v"(wf[kt]));
    }

    // layer0: x prefetch registers (t=0 issued before the loop); rows bg*16+r16
    float4 xf0[8], xf1[8];
    if (LAYER == 0) {
        const float* xp = x + (size_t)(bg * 16 + r16) * CC + q8;
        #pragma unroll
        for (int kt = 0; kt < 8; ++kt) {
            xf0[kt] = *(const float4*)(xp + kt * 32);
            xf1[kt] = *(const float4*)(xp + kt * 32 + 4);
        }
    }

    for (int i = 0; i <= TT; ++i) {
        const bool active = (LAYER == 0) ? (i < TT) : (i >= 1);
        const int t = (LAYER == 0) ? i : i - 1;
        float h = 0.f;
        if (active) {
            f32x4 a0 = {0.f,0.f,0.f,0.f}, a1 = {0.f,0.f,0.f,0.f};
            f32x4 a2 = {0.f,0.f,0.f,0.f}, a3 = {0.f,0.f,0.f,0.f};
            if (LAYER == 0) {
                // ---- staging: h0 rows -> LDS (x-proj overlaps flight) ----
                f32x4 stg[4];
                const char* srcA = (const char*)(h0base + (size_t)(t & 1) * S_ELEMS);
                #pragma unroll
                for (int k = 0; k < 4; ++k) {
                    int g = k * 4096 + tid * 16;
                    const char* sp = srcA + (size_t)(g >> 9) * 2048 + bg * 512 + (g & 511);
                    asm volatile("global_load_dwordx4 %0, %1, off sc0 sc1"
                                 : "=&v"(stg[k]) : "v"(sp) : "memory");
                }
                #pragma unroll
                for (int kt = 0; kt < 8; ++kt) {
                    bf16x8 a = pack8(xf0[kt], xf1[kt]);
                    bf16x8 wv = __builtin_bit_cast(bf16x8, wf[kt]);
                    f32x4& dst = (kt & 2) ? ((kt & 1) ? a3 : a2) : ((kt & 1) ? a1 : a0);
                    dst = __builtin_amdgcn_mfma_f32_16x16x32_bf16(a, wv, dst, 0, 0, 0);
                }
                asm volatile("s_waitcnt vmcnt(0)" ::: "memory");
                #pragma unroll
                for (int k = 0; k < 4; ++k) {
                    int g = k * 4096 + tid * 16;
                    int cgi = g >> 9, off = g & 511;
                    int m = off >> 5;
                    int lo = (cgi * 32 + (off & 16)) ^ ((m & 7) << 4);
                    *(f32x4*)(lds + m * 1024 + lo) = stg[k];
                }
                __syncthreads();
                #pragma unroll
                for (int kt = 0; kt < 16; ++kt) {
                    bf16x8 av = *(const bf16x8*)(lds + r16 * 1024 + ((kt * 64 + quad * 16) ^ sw));
                    bf16x8 wv = __builtin_bit_cast(bf16x8, wf[8 + kt]);
                    f32x4& dst = (kt & 2) ? ((kt & 1) ? a3 : a2) : ((kt & 1) ? a1 : a0);
                    dst = __builtin_amdgcn_mfma_f32_16x16x32_bf16(av, wv, dst, 0, 0, 0);
                }
            } else {
                // ---- split staging: h1 first, overlap h1-MFMAs with h0 flight ----
                f32x4 stg[8];
                const char* srcA = (const char*)(h0base + (size_t)((t + 1) & 1) * S_ELEMS);
                const char* srcB = (const char*)(h1base + (size_t)(t & 1) * S_ELEMS);
                #pragma unroll
                for (int k = 0; k < 8; ++k) {   // k<4: h1 (srcB); k>=4: h0 (srcA)
                    int g = (k & 3) * 4096 + tid * 16;
                    const char* sp = ((k < 4) ? srcB : srcA)
                                   + (size_t)(g >> 9) * 2048 + bg * 512 + (g & 511);
                    asm volatile("global_load_dwordx4 %0, %1, off sc0 sc1"
                                 : "=&v"(stg[k]) : "v"(sp) : "memory");
                }
                asm volatile("s_waitcnt vmcnt(4)" ::: "memory");   // h1 arrived
                __builtin_amdgcn_sched_barrier(0);
                #pragma unroll
                for (int k = 0; k < 4; ++k) {   // stage h1 -> lds[16384..)
                    int g = k * 4096 + tid * 16;
                    int cgi = g >> 9, off = g & 511;
                    int m = off >> 5;
                    int lo = (cgi * 32 + (off & 16)) ^ ((m & 7) << 4);
                    *(f32x4*)(lds + 16384 + m * 1024 + lo) = stg[k];
                }
                __syncthreads();
                #pragma unroll
                for (int kt = 16; kt < 32; ++kt) {  // h1-MFMAs overlap h0 flight
                    bf16x8 av = *(const bf16x8*)(lds + 16384 + r16 * 1024
                                                 + (((kt & 15) * 64 + quad * 16) ^ sw));
                    bf16x8 wv = __builtin_bit_cast(bf16x8, wf[kt]);
                    f32x4& dst = (kt & 2) ? ((kt & 1) ? a3 : a2) : ((kt & 1) ? a1 : a0);
                    dst = __builtin_amdgcn_mfma_f32_16x16x32_bf16(av, wv, dst, 0, 0, 0);
                }
                asm volatile("s_waitcnt vmcnt(0)" ::: "memory");
                __builtin_amdgcn_sched_barrier(0);
                #pragma unroll
                for (int k = 4; k < 8; ++k) {   // stage h0 -> lds[0..)
                    int g = (k & 3) * 4096 + tid * 16;
                    int cgi = g >> 9, off = g & 511;
                    int m = off >> 5;
                    int lo = (cgi * 32 + (off & 16)) ^ ((m & 7) << 4);
                    *(f32x4*)(lds + m * 1024 + lo) = stg[k];
                }
                __syncthreads();
                #pragma unroll
                for (int kt = 0; kt < 16; ++kt) {
                    bf16x8 av = *(const bf16x8*)(lds + r16 * 1024 + ((kt * 64 + quad * 16) ^ sw));
                    bf16x8 wv = __builtin_bit_cast(bf16x8, wf[kt]);
                    f32x4& dst = (kt & 2) ? ((kt & 1) ? a3 : a2) : ((kt & 1) ? a1 : a0);
                    dst = __builtin_amdgcn_mfma_f32_16x16x32_bf16(av, wv, dst, 0, 0, 0);
                }
            }
            f32x4 acc = (a0 + a1) + (a2 + a3);

            // gates for (myb, col): lanes sharing (quad,jj), gg = gate
            float gi = 0.f, gf = 0.f, gc = 0.f, go = 0.f;
            #pragma unroll
            for (int r = 0; r < 4; ++r) {
                float v0 = __shfl(acc[r], sl0, 64);
                float v1 = __shfl(acc[r], sl1, 64);
                float v2 = __shfl(acc[r], sl2, 64);
                float v3 = __shfl(acc[r], sl3, 64);
                if (r == gg) { gi = v0; gf = v1; gc = v2; go = v3; }
            }
            gi = sigf(gi + bi);
            gf = sigf(gf + bf_);
            gc = tanh_f(gc + bg_);
            go = sigf(go + bo);
            c = gf * c + gi * gc;
            h = go * tanh_f(c);

            // ---- pack 4 cols into u64, merge in LDS (full-line store path) ----
            u32 w0 = f2b_rne(h);
            u32 w1 = (u32)__shfl((int)w0, baseln + 1, 64);
            u32 w2 = (u32)__shfl((int)w0, baseln + 2, 64);
            u32 w3 = (u32)__shfl((int)w0, baseln + 3, 64);
            if (jj == 0) {
                u64 pkd = (u64)(w0 | (w1 << 16)) | ((u64)(w2 | (w3 << 16)) << 32);
                *(u64*)((char*)hstage + mb * 32 + wave * 8) = pkd;
            }
        }
        // ---- arrival: LDS-merge -> 32x16B contiguous stores -> drain -> add ----
        if (i < TT) {
            __syncthreads();   // hstage complete; also aligns inactive edge ticks
            if (active && tid < 32) {
                u16* hw = (LAYER == 0 ? h0base : h1base) + (size_t)((t + 1) & 1) * S_ELEMS;
                f32x4 v = *(const f32x4*)((const char*)hstage + tid * 16);
                const char* dp = (const char*)hw + (size_t)cg * 2048 + bg * 512 + tid * 16;
                asm volatile("global_store_dwordx4 %0, %1, off sc0 sc1"
                             :: "v"(dp), "v"(v) : "memory");
            }
            asm volatile("s_waitcnt vmcnt(0)" ::: "memory");
            __syncthreads();
            if (tid == 0) add_u32_sc(mycnt, 1u);
        }
        // ---- shadow work while adds propagate / peers finish ----
        if (active) {
            if (LAYER == 1) {
                float o1 = __shfl(h, baseln + 1, 64);
                float o2 = __shfl(h, baseln + 2, 64);
                float o3 = __shfl(h, baseln + 3, 64);
                if (jj == 0) {
                    float4 ov = { h, o1, o2, o3 };
                    *(float4*)(out + (size_t)t * S_ELEMS + (size_t)myb * HH
                               + cg * 16 + wave * 4) = ov;
                }
            }
            if (t == TT - 1) {
                float* fin = out + Y_ELEMS + (LAYER == 0 ? 0 : 2) * S_ELEMS;
                fin[myb * HH + col] = h;
                fin[S_ELEMS + myb * HH + col] = c;
            }
        }
        if (LAYER == 0 && i + 1 < TT) {      // prefetch x[t+1] into registers
            const float* xp = x + ((size_t)(i + 1) * BB + bg * 16 + r16) * CC + q8;
            #pragma unroll
            for (int kt = 0; kt < 8; ++kt) {
                xf0[kt] = *(const float4*)(xp + kt * 32);
                xf1[kt] = *(const float4*)(xp + kt * 32 + 4);
            }
        }
        // ---- completion: tid 67 (jj=3, no shadow stores) polls group's 4 lines ----
        if (i < TT) {
            const u32 tgt = (u32)(i + 1) * 16u;   // 16 blocks per counter line
            if (tid == 67) {
                while (true) {
                    u32 v0 = ld_u32_sc(gcnt + 0 * 32);
                    u32 v1 = ld_u32_sc(gcnt + 1 * 32);
                    u32 v2 = ld_u32_sc(gcnt + 2 * 32);
                    u32 v3 = ld_u32_sc(gcnt + 3 * 32);
                    u32 m = min(min(v0, v1), min(v2, v3));
                    if (m >= tgt) break;
                }
            }
            __syncthreads();
        }
    }
}

__global__ __launch_bounds__(256) __attribute__((amdgpu_waves_per_eu(1, 1)))
void k_lstm(const float* __restrict__ x,
            const float* __restrict__ c00,
            const float* __restrict__ c01,
            float* __restrict__ out,
            unsigned char* __restrict__ ws) {
    __shared__ __align__(16) unsigned char lds[33280];  // 32KB A-stage + 512B hstage
    const int bid = blockIdx.x;
    if (bid < 128) run_ticks<0>(x, c00, out, ws, bid, lds);
    else           run_ticks<1>(x, c01, out, ws, bid - 128, lds);
}

extern "C" void kernel_launch(void* const* d_in, const int* in_sizes, int n_in,
                              void* d_out, int out_size, void* d_ws, size_t ws_size,
                              hipStream_t stream) {
    const float* x    = (const float*)d_in[0];
    const float* h0_0 = (const float*)d_in[1];
    const float* c0_0 = (const float*)d_in[2];
    const float* h0_1 = (const float*)d_in[3];
    const float* c0_1 = (const float*)d_in[4];
    const float* Wih0 = (const float*)d_in[5];
    const float* Whh0 = (const float*)d_in[6];
    const float* bih0 = (const float*)d_in[7];
    const float* bhh0 = (const float*)d_in[8];
    const float* Wih1 = (const float*)d_in[9];
    const float* Whh1 = (const float*)d_in[10];
    const float* bih1 = (const float*)d_in[11];
    const float* bhh1 = (const float*)d_in[12];
    float* out = (float*)d_out;
    unsigned char* ws = (unsigned char*)d_ws;

    k_init<<<128, 256, 0, stream>>>(bih0, bhh0, bih1, bhh1, h0_0, h0_1, ws);
    k_wprep<<<1792, 256, 0, stream>>>(Wih0, Whh0, Wih1, Whh1, ws);
    k_lstm<<<256, 256, 0, stream>>>(x, c0_0, c0_1, out, ws);
}